// Round 6
// baseline (239.016 us; speedup 1.0000x reference)
//
#include <hip/hip_runtime.h>

typedef __bf16 bf16x8 __attribute__((ext_vector_type(8)));
typedef float f32x4 __attribute__((ext_vector_type(4)));

__device__ __forceinline__ unsigned short f2bf(float f) {
    union { float f; unsigned int u; } v; v.f = f;
    unsigned int u = v.u;
    unsigned int r = (u + 0x7fffu + ((u >> 16) & 1u)) >> 16;
    return (unsigned short)r;
}

// ---------------------------------------------------------------------------
// Kernel 1: reconstruct TT conv weights -> bf16, MFMA-A-fragment layout.
// kidx = (kh*3+kw)*128 + c ; stored wb[(kidx>>3)*2048 + d*8 + (kidx&7)]
// ---------------------------------------------------------------------------
__global__ void build_w_kernel(const float* __restrict__ core0,
                               const float* __restrict__ core1,
                               const float* __restrict__ core2,
                               unsigned short* __restrict__ wb) {
    __shared__ float s1[96];   // core1[d]: [r][kh][s]
    __shared__ float s2[12];   // core2[d]: [s][kw]
    const int d = blockIdx.x;
    const int c = threadIdx.x;   // 128 threads
    if (c < 96) s1[c] = core1[d * 96 + c];
    if (c >= 96 && c < 108) s2[c - 96] = core2[d * 12 + (c - 96)];
    __syncthreads();
    float t0[8];
#pragma unroll
    for (int r = 0; r < 8; ++r) t0[r] = core0[(d * 128 + c) * 8 + r];
#pragma unroll
    for (int kh = 0; kh < 3; ++kh) {
        float v[4] = {0.f, 0.f, 0.f, 0.f};
#pragma unroll
        for (int r = 0; r < 8; ++r)
#pragma unroll
            for (int s = 0; s < 4; ++s)
                v[s] += t0[r] * s1[(r * 3 + kh) * 4 + s];
#pragma unroll
        for (int kw = 0; kw < 3; ++kw) {
            float val = 0.f;
#pragma unroll
            for (int s = 0; s < 4; ++s) val += v[s] * s2[s * 3 + kw];
            const int kidx = (kh * 3 + kw) * 128 + c;
            wb[(kidx >> 3) * 2048 + d * 8 + (kidx & 7)] = f2bf(val);
        }
    }
}

// ---------------------------------------------------------------------------
// Kernel 2: implicit-GEMM conv, 512 threads / 8 waves, wave-row-split,
// pt-group-pipelined K-loop.
// Block (n, h-pair): out[n, 0:256, h0..h0+1, 0:64]. Waves 0-3 row h0,
// waves 4-7 row h0+1; per-wave tile 64d x 64w, acc[4][4] in AGPRs.
// Register budget is the binding constraint: 60 VGPR + 64 AGPR = 124 of the
// 128/wave that 2 blocks/CU (16 waves) allows. So B-frag ds_reads are
// software-pipelined at pt-GROUP granularity with ZERO added liveness:
// next chunk's bfr[pt-1] is issued right after this chunk's pt-th MFMA
// group (the register it fills was just freed by the consumed frag).
// Every ds_read gets >=2 MFMA groups (~150+ cyc) before use; A-frag global
// prefetch (1 chunk ahead) is issued after group 0 (~300 cyc L2 cover).
// Round-4 baseline: 94.6 us, MfmaUtil 34%, lgkm stall on every chunk.
// ---------------------------------------------------------------------------
#define LC 136   // padded c dim: byte stride 272 => 16B-granule stride 17 ≡ 1 (mod 8)

__global__ __launch_bounds__(512, 2) void conv_mfma_kernel(
    const float* __restrict__ x, const unsigned short* __restrict__ wb,
    const float* __restrict__ bias, float* __restrict__ out) {
    __shared__ __align__(16) unsigned short xl[4 * 66 * LC];   // 71,808 B

    const int tid  = threadIdx.x;
    const int lane = tid & 63;
    const int wv   = tid >> 6;          // 0..7
    const int l15  = lane & 15;
    const int quad = lane >> 4;
    const int bid  = blockIdx.x;
    const int n    = bid >> 5;          // 32 n
    const int h0   = (bid & 31) << 1;   // 32 h-pairs
    const int rowsel = wv >> 2;         // 0: row h0, 1: row h0+1

    // ---- zero halo columns (wcol 0 and 65) of all 4 slots ----
    if (tid < 128) {
        const int s   = tid >> 5;
        const int j   = tid & 31;
        const int col = (j >> 4) ? 65 : 0;
        const int c   = (j & 15) << 3;
        *(uint4*)(xl + (s * 66 + col) * LC + c) = make_uint4(0u, 0u, 0u, 0u);
    }

    // ---- stage image rows h0-1..h0+2 as bf16 [slot][wcol][c]; OOB -> zeros ----
#pragma unroll 2
    for (int i = 0; i < 4; ++i) {
        const int it  = tid + (i << 9);
        const int w4  = it & 15;
        const int cg  = (it >> 4) & 31;
        const int row = it >> 9;           // 0..3
        const int rimg = h0 + row - 1;
        float4 p0 = make_float4(0.f, 0.f, 0.f, 0.f), p1 = p0, p2 = p0, p3 = p0;
        const int c = cg << 2;
        const int w = w4 << 2;
        if (rimg >= 0 && rimg < 64) {
            const float4* gp = (const float4*)(x + (((n * 128 + c) * 64 + rimg) * 64 + w));
            p0 = gp[0];
            p1 = gp[1024];   // +1 c-plane (64*64 floats)
            p2 = gp[2048];
            p3 = gp[3072];
        }
        unsigned short* base = xl + (row * 66 + w + 1) * LC + c;
        *(ushort4*)(base)          = make_ushort4(f2bf(p0.x), f2bf(p1.x), f2bf(p2.x), f2bf(p3.x));
        *(ushort4*)(base + LC)     = make_ushort4(f2bf(p0.y), f2bf(p1.y), f2bf(p2.y), f2bf(p3.y));
        *(ushort4*)(base + 2 * LC) = make_ushort4(f2bf(p0.z), f2bf(p1.z), f2bf(p2.z), f2bf(p3.z));
        *(ushort4*)(base + 3 * LC) = make_ushort4(f2bf(p0.w), f2bf(p1.w), f2bf(p2.w), f2bf(p3.w));
    }

    f32x4 acc[4][4];
#pragma unroll
    for (int a0 = 0; a0 < 4; ++a0)
#pragma unroll
        for (int b0 = 0; b0 < 4; ++b0) acc[a0][b0] = (f32x4){0.f, 0.f, 0.f, 0.f};

    const int dwave = (wv & 3) << 6;                 // 64 d per wave
    const bf16x8* wgv = (const bf16x8*)wb;           // 16 B granules
    const int abase = quad * 256 + dwave + l15;      // lane's frag index within a chunk

    // A-frag double buffer: prefetch chunk 0 before the barrier (global, no dep)
    bf16x8 abuf[2][4];
#pragma unroll
    for (int dt = 0; dt < 4; ++dt) abuf[0][dt] = wgv[abase + dt * 16];

    __syncthreads();   // the ONLY barrier

    // B base: rowsel picks the wave's image-row window (slots rowsel..rowsel+2)
    const unsigned short* bb = xl + (rowsel * 66 + l15) * LC + quad * 8;

    // B-frag double buffer: load chunk 0's 4 frags
    bf16x8 bbuf[2][4];
#pragma unroll
    for (int pt = 0; pt < 4; ++pt) {
        // chunk 0: tap 0 (kh=0,kw=0), c4=0
        bbuf[0][pt] = *(const bf16x8*)(bb + pt * 16 * LC);
    }

#pragma unroll
    for (int ch = 0; ch < 36; ++ch) {
        const int cur = ch & 1;
        const int nxt = cur ^ 1;
        const bool more = (ch + 1) < 36;
        // next chunk's B address components (compile-time after unroll)
        const int ntap = (ch + 1) >> 2;
        const int nc4  = (ch + 1) & 3;
        const int nkh  = ntap / 3;
        const int nkw  = ntap - nkh * 3;
        const unsigned short* nbp = bb + (nkh * 66 + nkw) * LC + (nc4 << 5);

        // ---- group 0 ----
#pragma unroll
        for (int dt = 0; dt < 4; ++dt)
            acc[dt][0] = __builtin_amdgcn_mfma_f32_16x16x32_bf16(
                abuf[cur][dt], bbuf[cur][0], acc[dt][0], 0, 0, 0);
        if (more) {   // A prefetch for chunk ch+1: ~3 groups of cover
            const bf16x8* g2 = wgv + (ch + 1) * 1024 + abase;
#pragma unroll
            for (int dt = 0; dt < 4; ++dt) abuf[nxt][dt] = g2[dt * 16];
        }
        // ---- group 1 ----
#pragma unroll
        for (int dt = 0; dt < 4; ++dt)
            acc[dt][1] = __builtin_amdgcn_mfma_f32_16x16x32_bf16(
                abuf[cur][dt], bbuf[cur][1], acc[dt][1], 0, 0, 0);
        if (more) bbuf[nxt][0] = *(const bf16x8*)(nbp);
        // ---- group 2 ----
#pragma unroll
        for (int dt = 0; dt < 4; ++dt)
            acc[dt][2] = __builtin_amdgcn_mfma_f32_16x16x32_bf16(
                abuf[cur][dt], bbuf[cur][2], acc[dt][2], 0, 0, 0);
        if (more) bbuf[nxt][1] = *(const bf16x8*)(nbp + 16 * LC);
        // ---- group 3 ----
#pragma unroll
        for (int dt = 0; dt < 4; ++dt)
            acc[dt][3] = __builtin_amdgcn_mfma_f32_16x16x32_bf16(
                abuf[cur][dt], bbuf[cur][3], acc[dt][3], 0, 0, 0);
        if (more) {
            bbuf[nxt][2] = *(const bf16x8*)(nbp + 32 * LC);
            bbuf[nxt][3] = *(const bf16x8*)(nbp + 48 * LC);
        }
    }

    // ---- epilogue: bias + store. D layout: row(d)=quad*4+rr, col(w)=l15 ----
    const float bv = bias[0];
    const int oh = h0 + rowsel;
#pragma unroll
    for (int dt = 0; dt < 4; ++dt) {
#pragma unroll
        for (int pt = 0; pt < 4; ++pt) {
#pragma unroll
            for (int rr = 0; rr < 4; ++rr) {
                const int d = dwave + dt * 16 + quad * 4 + rr;
                const int w = pt * 16 + l15;
                out[((n * 256 + d) * 64 + oh) * 64 + w] = acc[dt][pt][rr] + bv;
            }
        }
    }
}

extern "C" void kernel_launch(void* const* d_in, const int* in_sizes, int n_in,
                              void* d_out, int out_size, void* d_ws, size_t ws_size,
                              hipStream_t stream) {
    const float* x     = (const float*)d_in[0];
    const float* core0 = (const float*)d_in[1];
    const float* core1 = (const float*)d_in[2];
    const float* core2 = (const float*)d_in[3];
    const float* bias  = (const float*)d_in[4];
    unsigned short* wb = (unsigned short*)d_ws;   // 1152*256*2 = 589,824 B

    build_w_kernel<<<256, 128, 0, stream>>>(core0, core1, core2, wb);
    conv_mfma_kernel<<<1024, 512, 0, stream>>>(x, wb, bias, (float*)d_out);
}